// Round 6
// baseline (29975.504 us; speedup 1.0000x reference)
//
#include <hip/hip_runtime.h>
#include <hip/hip_bf16.h>
#include <stdint.h>

// Problem constants (fixed by the reference): T=512, B=64, IN=H=1024, L=2
#define TT 512
#define BB 64
#define HH 1024
#define BH 65536    // B*H elements
#define KD 2048     // IN+H == H+H

typedef __attribute__((ext_vector_type(8))) short short8;
typedef __attribute__((ext_vector_type(4))) float f32x4;

__device__ __forceinline__ unsigned short f2bf(float f) {
  union { float f; unsigned int u; } v; v.f = f;
  unsigned int r = v.u + 0x7fffu + ((v.u >> 16) & 1u);  // RNE
  return (unsigned short)(r >> 16);
}
__device__ __forceinline__ float fsig(float x)  { return 1.0f / (1.0f + __expf(-x)); }
__device__ __forceinline__ float ftanhf(float x){ return 1.0f - 2.0f / (__expf(2.0f * x) + 1.0f); }

// ---------------- x -> bf16 ----------------
__global__ void cvt_x_kernel(const float* __restrict__ x, unsigned short* __restrict__ xbf) {
  const int n4 = (TT * BB * 1024) / 4;
  int stride = gridDim.x * blockDim.x;
  for (int i = blockIdx.x * blockDim.x + threadIdx.x; i < n4; i += stride) {
    float4 v = ((const float4*)x)[i];
    unsigned long long p = (unsigned long long)f2bf(v.x)
        | ((unsigned long long)f2bf(v.y) << 16)
        | ((unsigned long long)f2bf(v.z) << 32)
        | ((unsigned long long)f2bf(v.w) << 48);
    ((unsigned long long*)xbf)[i] = p;
  }
}

// ---------------- W [4096][2048] f32 -> bf16 slices [128][32][2048] ----------------
// slice g, row r: nt=r>>4, q=(r>>2)&3, jl=r&3 ; W row = q*1024 + g*8 + nt*4 + jl
__global__ void cvt_w_kernel(const float* __restrict__ W, unsigned short* __restrict__ Ws) {
  int idx = blockIdx.x * blockDim.x + threadIdx.x;   // < 128*32*512
  int k4 = idx & 511;
  int r  = (idx >> 9) & 31;
  int g  = idx >> 14;
  int grow = (((r >> 2) & 3) << 10) + (g << 3) + ((r >> 4) << 2) + (r & 3);
  float4 v = ((const float4*)(W + (size_t)grow * KD))[k4];
  unsigned long long p = (unsigned long long)f2bf(v.x)
      | ((unsigned long long)f2bf(v.y) << 16)
      | ((unsigned long long)f2bf(v.z) << 32)
      | ((unsigned long long)f2bf(v.w) << 48);
  ((unsigned long long*)(Ws + (((size_t)(g * 32 + r)) << 11)))[k4] = p;
}

// ---------------- initial h -> slot 0 of parity-4 buffers ----------------
__global__ void init_state_kernel(const float* __restrict__ h0in,
                                  unsigned short* h0b, unsigned short* h1b) {
  int i = blockIdx.x * blockDim.x + threadIdx.x;  // < BH
  h0b[i] = f2bf(h0in[i]);
  h1b[i] = f2bf(h0in[BH + i]);
}

// tid0-only: spin until the 8 sub-counters (256B apart) sum to 128
__device__ __forceinline__ void poll128(int* base) {
  for (;;) {
    int s = 0;
#pragma unroll
    for (int j = 0; j < 8; j++)
      s += __hip_atomic_load(base + (j << 6), __ATOMIC_RELAXED, __HIP_MEMORY_SCOPE_AGENT);
    if (s >= 128) return;
    __builtin_amdgcn_s_sleep(1);
  }
}

// ---------------- persistent 2-layer LSTM, phase-split around the wait ----------------
// 256 blocks x 512 threads, 1 block/CU. Blocks 0-127: layer0 (step t),
// 128-255: layer1 lag-2 (step u=t-2). Weights resident in 128KB LDS; c in regs.
// h in 4 parity slots/layer; ALL h traffic is sc1 (L2-bypassed agent atomics):
// stores packed 2xbf16, loads 4x4B -> short8. Dependency-free half-GEMM
// (L0: x-half; L1: h0-half, 2-step slack) runs BEFORE the tight wait.
// Counters: cnt0[t] (L0 done outer t), cnt1[t] (L1 done outer t); 8 sub-words.
// Waits:  L0@t: cnt0[t-1] (tight) + cnt1[t-2] (slot anti-dep, slack 2)
//         L1@t: cnt0[t-2] (slack 2, before phase A) + cnt1[t-1] (tight)
__global__ __launch_bounds__(512) void lstm_persist(
    const unsigned short* __restrict__ W0s, const unsigned short* __restrict__ W1s,
    const float* __restrict__ b0, const float* __restrict__ b1,
    const unsigned short* __restrict__ xbf,
    unsigned short* h0buf, unsigned short* h1buf,   // 4 slots each, stride BH
    const float* __restrict__ c0in, float* out, int* cnt)
{
  __shared__ unsigned short wlds[32 * KD];   // 128 KB
  const int tid = threadIdx.x;
  const int bid = blockIdx.x;
  const int layer = bid >> 7;
  const int g = bid & 127;

  const unsigned short* Ws = layer ? W1s : W0s;
  const float* bias = layer ? b1 : b0;
  int* const cnt0 = cnt;                    // cnt0[t] at cnt + (t<<9), t in [0,TT)
  int* const cnt1 = cnt + (530 << 9);       // cnt1[t] at cnt1 + (t<<9), t in [2,TT+2)

  // ---- stage weight slice once (swizzled on the write side) ----
  {
    const unsigned short* wsrc = Ws + ((size_t)g << 16);  // g*32*2048
    int r   = tid >> 4;          // 0..31 row
    int sub = tid & 15;
    int swz = (r & 7) << 4;
#pragma unroll
    for (int it = 0; it < 16; it++) {
      int cbyte = (sub + it * 16) << 4;
      short8 v = *(const short8*)((const char*)wsrc + r * 4096 + cbyte);
      *(short8*)((char*)wlds + r * 4096 + (cbyte ^ swz)) = v;
    }
  }

  // ---- wave / lane mapping ----
  const int lane = tid & 63;
  const int w  = tid >> 6;        // 0..7
  const int mt = w & 3;           // m-tile (batch)
  const int nt = w >> 2;          // n-tile 0..1
  const int m0 = mt << 4;
  const int n  = lane & 15;
  const int hi = lane >> 4;
  const int jl = n & 3;
  const int jg = (g << 3) + (nt << 2) + jl;    // h column 0..1023
  const int nrow = (nt << 4) + n;              // LDS weight row
  const char* brow = (const char*)wlds + (nrow << 12);
  const int bswz = (nrow & 7) << 4;
  const int rowoff32 = ((m0 + n) << 9) + (hi << 2);   // row base in u32 units

  // ---- c state in registers (lanes n<4 hold 4 values each) ----
  float creg[4];
  float bi = 0.f, bfv = 0.f, bgv = 0.f, bov = 0.f;
  if (n < 4) {
    bi  = bias[jg];
    bfv = bias[1024 + jg];
    bgv = bias[2048 + jg];
    bov = bias[3072 + jg];
#pragma unroll
    for (int r = 0; r < 4; r++) {
      int m = m0 + (hi << 2) + r;
      creg[r] = c0in[(size_t)layer * BH + (m << 10) + jg];
    }
  }
  __syncthreads();

  for (int t = 0; t <= TT + 1; t++) {
    const bool active = (layer == 0) ? (t < TT) : (t >= 2);
    const int u = t - 2;                       // L1 step index
    f32x4 acc = {0.0f, 0.0f, 0.0f, 0.0f};

    // ---------- PHASE A: slack input x first K-half of W ----------
    if (layer == 1 && active) {                // needs h0out[u] = value t-1
      if (tid == 0) poll128(cnt0 + ((size_t)(t - 2) << 9));
      __syncthreads();
    }
    if (active) {
      if (layer == 0) {
        const unsigned short* arow = xbf + (size_t)t * BH + ((size_t)(m0 + n) << 10) + (hi << 3);
#pragma unroll 8
        for (int kk = 0; kk < 32; kk++) {
          short8 av = *(const short8*)(arow + (kk << 5));
          short8 bv = *(const short8*)(brow + (((kk << 6) + (hi << 4)) ^ bswz));
          acc = __builtin_amdgcn_mfma_f32_16x16x32_bf16(av, bv, acc, 0, 0, 0);
        }
      } else {
        const unsigned int* hrow = (const unsigned int*)(h0buf + (size_t)((t - 1) & 3) * BH) + rowoff32;
#pragma unroll 4
        for (int kk = 0; kk < 32; kk++) {
          union { unsigned int wd[4]; short8 s; } a;
          const unsigned int* p = hrow + (kk << 4);
          a.wd[0] = __hip_atomic_load((int*)(p + 0), __ATOMIC_RELAXED, __HIP_MEMORY_SCOPE_AGENT);
          a.wd[1] = __hip_atomic_load((int*)(p + 1), __ATOMIC_RELAXED, __HIP_MEMORY_SCOPE_AGENT);
          a.wd[2] = __hip_atomic_load((int*)(p + 2), __ATOMIC_RELAXED, __HIP_MEMORY_SCOPE_AGENT);
          a.wd[3] = __hip_atomic_load((int*)(p + 3), __ATOMIC_RELAXED, __HIP_MEMORY_SCOPE_AGENT);
          short8 bv = *(const short8*)(brow + (((kk << 6) + (hi << 4)) ^ bswz));
          acc = __builtin_amdgcn_mfma_f32_16x16x32_bf16(a.s, bv, acc, 0, 0, 0);
        }
      }
    }

    // ---------- tight wait (own-layer recurrence + anti-dep) ----------
    if (layer == 0) {
      if (t >= 1 && t < TT) {
        if (tid == 0) {
          poll128(cnt0 + ((size_t)(t - 1) << 9));
          if (t >= 4) poll128(cnt1 + ((size_t)(t - 2) << 9));
        }
        __syncthreads();
      }
    } else {
      if (t >= 3) {
        if (tid == 0) poll128(cnt1 + ((size_t)(t - 1) << 9));
        __syncthreads();
      }
    }

    // ---------- PHASE B: own-layer h x second K-half + epilogue ----------
    if (active) {
      const unsigned short* hsrc = (layer == 0) ? (h0buf + (size_t)(t & 3) * BH)
                                                : (h1buf + (size_t)(u & 3) * BH);
      const unsigned int* hrow = (const unsigned int*)hsrc + rowoff32;
#pragma unroll 4
      for (int kk = 0; kk < 32; kk++) {
        union { unsigned int wd[4]; short8 s; } a;
        const unsigned int* p = hrow + (kk << 4);
        a.wd[0] = __hip_atomic_load((int*)(p + 0), __ATOMIC_RELAXED, __HIP_MEMORY_SCOPE_AGENT);
        a.wd[1] = __hip_atomic_load((int*)(p + 1), __ATOMIC_RELAXED, __HIP_MEMORY_SCOPE_AGENT);
        a.wd[2] = __hip_atomic_load((int*)(p + 2), __ATOMIC_RELAXED, __HIP_MEMORY_SCOPE_AGENT);
        a.wd[3] = __hip_atomic_load((int*)(p + 3), __ATOMIC_RELAXED, __HIP_MEMORY_SCOPE_AGENT);
        short8 bv = *(const short8*)(brow + ((2048 + (kk << 6) + (hi << 4)) ^ bswz));
        acc = __builtin_amdgcn_mfma_f32_16x16x32_bf16(a.s, bv, acc, 0, 0, 0);
      }

      unsigned short* hb = (layer == 0) ? (h0buf + (size_t)((t + 1) & 3) * BH)
                                        : (h1buf + (size_t)((u + 1) & 3) * BH);
      unsigned int* hb32 = (unsigned int*)hb;
      float* hf = nullptr;                               // f32 row destination
      if (layer == 1) hf = out + (size_t)u * BH;         // hlast[u]
      else if (t == TT - 1) hf = out + (size_t)TT * BH;  // final h, layer 0

      const int src = (lane & 48) | jl;
#pragma unroll
      for (int r = 0; r < 4; r++) {
        float vi = __shfl(acc[r], src,      64);
        float vf = __shfl(acc[r], src | 4,  64);
        float vg = __shfl(acc[r], src | 8,  64);
        float vo = __shfl(acc[r], src | 12, 64);
        float hn = 0.f, cn = 0.f;
        int m = m0 + (hi << 2) + r;
        int idx = (m << 10) + jg;
        if (n < 4) {
          float ig = fsig(vi + bi);
          float fg = fsig(vf + bfv);
          float gg = ftanhf(vg + bgv);
          float og = fsig(vo + bov);
          cn = ig * gg + fg * creg[r];
          hn = og * ftanhf(cn);
          creg[r] = cn;
          if (layer == 1 && u == TT - 1) {
            out[(size_t)TT * BH + BH + idx] = hn;        // final h, layer 1
            out[(size_t)TT * BH + 3 * BH + idx] = cn;    // final c, layer 1
          }
          if (layer == 0 && t == TT - 1) {
            out[(size_t)TT * BH + 2 * BH + idx] = cn;    // final c, layer 0
          }
        }
        float hn2 = __shfl(hn, lane + 1, 64);
        if (n < 4 && (n & 1) == 0) {
          unsigned int pack = (unsigned int)f2bf(hn) | ((unsigned int)f2bf(hn2) << 16);
          __hip_atomic_store(hb32 + (idx >> 1), pack, __ATOMIC_RELAXED, __HIP_MEMORY_SCOPE_AGENT);
          if (hf) *(float2*)(hf + idx) = make_float2(hn, hn2);
        }
      }
    }

    // ---------- publish: drain (per-wave vmcnt0 at barrier), then 1 atomicAdd ----------
    __syncthreads();
    if (tid == 0) {
      if (layer == 0) {
        if (t < TT) atomicAdd(cnt0 + ((size_t)t << 9) + ((g & 7) << 6), 1);
      } else if (t >= 2) {
        atomicAdd(cnt1 + ((size_t)t << 9) + ((g & 7) << 6), 1);
      }
    }
    if (layer == 0 && t >= TT - 1) break;   // L0 done; L1 runs to TT+1
  }
}

extern "C" void kernel_launch(void* const* d_in, const int* in_sizes, int n_in,
                              void* d_out, int out_size, void* d_ws, size_t ws_size,
                              hipStream_t stream) {
  (void)in_sizes; (void)n_in; (void)out_size; (void)ws_size;
  const float* x    = (const float*)d_in[0];
  const float* h0in = (const float*)d_in[1];
  const float* c0in = (const float*)d_in[2];
  const float* W0   = (const float*)d_in[3];
  const float* b0   = (const float*)d_in[4];
  const float* W1   = (const float*)d_in[5];
  const float* b1   = (const float*)d_in[6];
  float* out = (float*)d_out;

  char* ws = (char*)d_ws;
  unsigned short* Xbf   = (unsigned short*)(ws);                 // 64 MB
  unsigned short* W0s   = (unsigned short*)(ws + 67108864);      // 16 MB
  unsigned short* W1s   = (unsigned short*)(ws + 83886080);      // 16 MB
  unsigned short* h0buf = (unsigned short*)(ws + 100663296);     // 4*128KB
  unsigned short* h1buf = (unsigned short*)(ws + 101187584);     // 4*128KB
  int* cnt              = (int*)(ws + 101711872);                // ~2.2 MB counters

  const size_t CNT_BYTES = (size_t)(530 + TT + 4) * 512 * sizeof(int);
  hipMemsetAsync(cnt, 0, CNT_BYTES, stream);
  cvt_x_kernel<<<2048, 256, 0, stream>>>(x, Xbf);
  cvt_w_kernel<<<8192, 256, 0, stream>>>(W0, W0s);
  cvt_w_kernel<<<8192, 256, 0, stream>>>(W1, W1s);
  init_state_kernel<<<256, 256, 0, stream>>>(h0in, h0buf, h1buf);

  lstm_persist<<<256, 512, 0, stream>>>(W0s, W1s, b0, b1, Xbf,
                                        h0buf, h1buf, c0in, out, cnt);
}

// Round 7
// 8441.155 us; speedup vs baseline: 3.5511x; 3.5511x over previous
//
#include <hip/hip_runtime.h>
#include <hip/hip_bf16.h>
#include <stdint.h>

// Problem constants (fixed by the reference): T=512, B=64, IN=H=1024, L=2
#define TT 512
#define BB 64
#define HH 1024
#define BH 65536    // B*H elements
#define KD 2048     // IN+H == H+H

typedef __attribute__((ext_vector_type(8))) short short8;
typedef __attribute__((ext_vector_type(4))) float f32x4;

__device__ __forceinline__ unsigned short f2bf(float f) {
  union { float f; unsigned int u; } v; v.f = f;
  unsigned int r = v.u + 0x7fffu + ((v.u >> 16) & 1u);  // RNE
  return (unsigned short)(r >> 16);
}
__device__ __forceinline__ float fsig(float x)  { return 1.0f / (1.0f + __expf(-x)); }
__device__ __forceinline__ float ftanhf(float x){ return 1.0f - 2.0f / (__expf(2.0f * x) + 1.0f); }

// ---------------- x -> bf16 ----------------
__global__ void cvt_x_kernel(const float* __restrict__ x, unsigned short* __restrict__ xbf) {
  const int n4 = (TT * BB * 1024) / 4;
  int stride = gridDim.x * blockDim.x;
  for (int i = blockIdx.x * blockDim.x + threadIdx.x; i < n4; i += stride) {
    float4 v = ((const float4*)x)[i];
    unsigned long long p = (unsigned long long)f2bf(v.x)
        | ((unsigned long long)f2bf(v.y) << 16)
        | ((unsigned long long)f2bf(v.z) << 32)
        | ((unsigned long long)f2bf(v.w) << 48);
    ((unsigned long long*)xbf)[i] = p;
  }
}

// ---------------- W [4096][2048] f32 -> bf16 slices [128][32][2048] ----------------
// slice g, row r: nt=r>>4, q=(r>>2)&3, jl=r&3 ; W row = q*1024 + g*8 + nt*4 + jl
__global__ void cvt_w_kernel(const float* __restrict__ W, unsigned short* __restrict__ Ws) {
  int idx = blockIdx.x * blockDim.x + threadIdx.x;   // < 128*32*512
  int k4 = idx & 511;
  int r  = (idx >> 9) & 31;
  int g  = idx >> 14;
  int grow = (((r >> 2) & 3) << 10) + (g << 3) + ((r >> 4) << 2) + (r & 3);
  float4 v = ((const float4*)(W + (size_t)grow * KD))[k4];
  unsigned long long p = (unsigned long long)f2bf(v.x)
      | ((unsigned long long)f2bf(v.y) << 16)
      | ((unsigned long long)f2bf(v.z) << 32)
      | ((unsigned long long)f2bf(v.w) << 48);
  ((unsigned long long*)(Ws + (((size_t)(g * 32 + r)) << 11)))[k4] = p;
}

// ---------------- initial h -> hist slot 0 ----------------
__global__ void init_state_kernel(const float* __restrict__ h0in,
                                  unsigned short* h0s0, unsigned short* h1s0) {
  int i = blockIdx.x * blockDim.x + threadIdx.x;  // < BH
  h0s0[i] = f2bf(h0in[i]);
  h1s0[i] = f2bf(h0in[BH + i]);
}

// tid0-only: spin until the 8 sub-counters (256B apart) sum to 128
__device__ __forceinline__ void poll128(int* base) {
  for (;;) {
    int s = 0;
#pragma unroll
    for (int j = 0; j < 8; j++)
      s += __hip_atomic_load(base + (j << 6), __ATOMIC_RELAXED, __HIP_MEMORY_SCOPE_AGENT);
    if (s >= 128) return;
    __builtin_amdgcn_s_sleep(1);
  }
}

// ---------------- persistent 2-layer LSTM: phase-split + write-once history ----------------
// 256 blocks x 512 threads, 1 block/CU. Blocks 0-127: layer0 (outer step t),
// 128-255: layer1 at lag 2 (u = t-2). Weights resident in 128KB LDS; c in regs.
// h via WRITE-ONCE history (h?hist[s] = h after s steps): plain cached dwordx4
// loads (stale-impossible), packed-2xbf16 sc1 stores (write-through to LLC).
// PHASE A (before tight wait): L0 computes x-half, L1 computes h0-half
// (h0hist[u+1], guaranteed by pre-A poll of cnt0[u], 2 steps of slack).
// Tight wait: L0 -> cnt0[t-1] only (self-chain, decoupled from L1);
//             L1 -> cnt1[u-1]. PHASE B: own-layer h-half + epilogue.
// Publish: __syncthreads (vmcnt0 drain) then one atomicAdd to 8-way-split cnt.
__global__ __launch_bounds__(512) void lstm_persist(
    const unsigned short* __restrict__ W0s, const unsigned short* __restrict__ W1s,
    const float* __restrict__ b0, const float* __restrict__ b1,
    const unsigned short* __restrict__ xbf,
    unsigned short* h0hist, unsigned short* h1hist,
    const float* __restrict__ c0in, float* out, int* cnt)
{
  __shared__ unsigned short wlds[32 * KD];   // 128 KB
  const int tid = threadIdx.x;
  const int bid = blockIdx.x;
  const int layer = bid >> 7;
  const int g = bid & 127;

  const unsigned short* Ws = layer ? W1s : W0s;
  const float* bias = layer ? b1 : b0;
  int* const cnt0 = cnt;                  // cnt0[t], t in [0,TT): stride 512 ints
  int* const cnt1 = cnt + (530 << 9);     // cnt1[u], u in [0,TT): stride 512 ints

  // ---- stage weight slice once (swizzled on the write side) ----
  {
    const unsigned short* wsrc = Ws + ((size_t)g << 16);  // g*32*2048
    int r   = tid >> 4;          // 0..31 row
    int sub = tid & 15;
    int swz = (r & 7) << 4;
#pragma unroll
    for (int it = 0; it < 16; it++) {
      int cbyte = (sub + it * 16) << 4;
      short8 v = *(const short8*)((const char*)wsrc + r * 4096 + cbyte);
      *(short8*)((char*)wlds + r * 4096 + (cbyte ^ swz)) = v;
    }
  }

  // ---- wave / lane mapping ----
  const int lane = tid & 63;
  const int w  = tid >> 6;        // 0..7
  const int mt = w & 3;           // m-tile (batch)
  const int nt = w >> 2;          // n-tile 0..1
  const int m0 = mt << 4;
  const int n  = lane & 15;
  const int hi = lane >> 4;
  const int jl = n & 3;
  const int jg = (g << 3) + (nt << 2) + jl;    // h column 0..1023
  const int nrow = (nt << 4) + n;              // LDS weight row
  const char* brow = (const char*)wlds + (nrow << 12);
  const int bswz = (nrow & 7) << 4;
  const int rowoff = ((m0 + n) << 10) + (hi << 3);  // A-row base (elements)

  // ---- c state in registers (lanes n<4 hold 4 values each) ----
  float creg[4];
  float bi = 0.f, bfv = 0.f, bgv = 0.f, bov = 0.f;
  if (n < 4) {
    bi  = bias[jg];
    bfv = bias[1024 + jg];
    bgv = bias[2048 + jg];
    bov = bias[3072 + jg];
#pragma unroll
    for (int r = 0; r < 4; r++) {
      int m = m0 + (hi << 2) + r;
      creg[r] = c0in[(size_t)layer * BH + (m << 10) + jg];
    }
  }
  __syncthreads();

  for (int t = 0; t <= TT + 1; t++) {
    const bool active = (layer == 0) ? (t < TT) : (t >= 2);
    const int u = t - 2;                       // L1 step index
    f32x4 acc = {0.0f, 0.0f, 0.0f, 0.0f};

    // ---------- pre-A wait (L1 only): h0hist[u+1] complete (2-step slack) ----------
    if (layer == 1 && active) {
      if (tid == 0) poll128(cnt0 + ((size_t)u << 9));
      __syncthreads();
    }

    // ---------- PHASE A: dependency-free input x first K-half ----------
    if (active) {
      const unsigned short* in0 = (layer == 0)
          ? xbf + (size_t)t * BH
          : h0hist + (size_t)(u + 1) * BH;
      const unsigned short* arow0 = in0 + rowoff;
#pragma unroll 8
      for (int kk = 0; kk < 32; kk++) {
        short8 av = *(const short8*)(arow0 + (kk << 5));
        short8 bv = *(const short8*)(brow + (((kk << 6) + (hi << 4)) ^ bswz));
        acc = __builtin_amdgcn_mfma_f32_16x16x32_bf16(av, bv, acc, 0, 0, 0);
      }
    }

    // ---------- tight wait (own-layer recurrence only) ----------
    if (layer == 0) {
      if (t >= 1 && t < TT) {
        if (tid == 0) poll128(cnt0 + ((size_t)(t - 1) << 9));
        __syncthreads();
      }
    } else {
      if (t >= 3) {
        if (tid == 0) poll128(cnt1 + ((size_t)(u - 1) << 9));
        __syncthreads();
      }
    }

    // ---------- PHASE B: own-layer h x second K-half + epilogue ----------
    if (active) {
      const unsigned short* in1 = (layer == 0) ? h0hist + (size_t)t * BH
                                               : h1hist + (size_t)u * BH;
      const unsigned short* arow1 = in1 + rowoff;
#pragma unroll 8
      for (int kk = 0; kk < 32; kk++) {
        short8 av = *(const short8*)(arow1 + (kk << 5));
        short8 bv = *(const short8*)(brow + ((2048 + (kk << 6) + (hi << 4)) ^ bswz));
        acc = __builtin_amdgcn_mfma_f32_16x16x32_bf16(av, bv, acc, 0, 0, 0);
      }

      unsigned short* hb = (layer == 0) ? h0hist + (size_t)(t + 1) * BH
                                        : h1hist + (size_t)(u + 1) * BH;
      unsigned int* hb32 = (unsigned int*)hb;
      float* hf = nullptr;                               // f32 row destination
      if (layer == 1) hf = out + (size_t)u * BH;         // hlast[u]
      else if (t == TT - 1) hf = out + (size_t)TT * BH;  // final h, layer 0

      const int src = (lane & 48) | jl;
#pragma unroll
      for (int r = 0; r < 4; r++) {
        float vi = __shfl(acc[r], src,      64);
        float vf = __shfl(acc[r], src | 4,  64);
        float vg = __shfl(acc[r], src | 8,  64);
        float vo = __shfl(acc[r], src | 12, 64);
        float hn = 0.f;
        int m = m0 + (hi << 2) + r;
        int idx = (m << 10) + jg;
        if (n < 4) {
          float ig = fsig(vi + bi);
          float fg = fsig(vf + bfv);
          float gg = ftanhf(vg + bgv);
          float og = fsig(vo + bov);
          float cn = ig * gg + fg * creg[r];
          hn = og * ftanhf(cn);
          creg[r] = cn;
          if (layer == 1 && u == TT - 1) {
            out[(size_t)TT * BH + BH + idx] = hn;        // final h, layer 1
            out[(size_t)TT * BH + 3 * BH + idx] = cn;    // final c, layer 1
          }
          if (layer == 0 && t == TT - 1) {
            out[(size_t)TT * BH + 2 * BH + idx] = cn;    // final c, layer 0
          }
        }
        float hn2 = __shfl(hn, lane + 1, 64);
        if (n < 4 && (n & 1) == 0) {
          unsigned int pack = (unsigned int)f2bf(hn) | ((unsigned int)f2bf(hn2) << 16);
          __hip_atomic_store(hb32 + (idx >> 1), pack, __ATOMIC_RELAXED, __HIP_MEMORY_SCOPE_AGENT);
          if (hf) *(float2*)(hf + idx) = make_float2(hn, hn2);
        }
      }
    }

    // ---------- publish: drain stores (vmcnt0 at barrier), then 1 atomicAdd ----------
    __syncthreads();
    if (tid == 0) {
      if (layer == 0) {
        if (t < TT) atomicAdd(cnt0 + ((size_t)t << 9) + ((g & 7) << 6), 1);
      } else if (t >= 2) {
        atomicAdd(cnt1 + ((size_t)u << 9) + ((g & 7) << 6), 1);
      }
    }
    if (layer == 0 && t >= TT - 1) break;   // L0 done; L1 runs to TT+1
  }
}

extern "C" void kernel_launch(void* const* d_in, const int* in_sizes, int n_in,
                              void* d_out, int out_size, void* d_ws, size_t ws_size,
                              hipStream_t stream) {
  (void)in_sizes; (void)n_in; (void)out_size; (void)ws_size;
  const float* x    = (const float*)d_in[0];
  const float* h0in = (const float*)d_in[1];
  const float* c0in = (const float*)d_in[2];
  const float* W0   = (const float*)d_in[3];
  const float* b0   = (const float*)d_in[4];
  const float* W1   = (const float*)d_in[5];
  const float* b1   = (const float*)d_in[6];
  float* out = (float*)d_out;

  char* ws = (char*)d_ws;
  const size_t HIST = (size_t)(TT + 1) * BH * sizeof(unsigned short);  // 67,239,936 B
  unsigned short* Xbf    = (unsigned short*)(ws);                      // 64 MB
  unsigned short* W0s    = (unsigned short*)(ws + 67108864);           // 16 MB
  unsigned short* W1s    = (unsigned short*)(ws + 83886080);           // 16 MB
  unsigned short* h0hist = (unsigned short*)(ws + 100663296);          // 64.1 MB
  unsigned short* h1hist = (unsigned short*)(ws + 100663296 + HIST);   // 64.1 MB
  int* cnt               = (int*)(ws + 100663296 + 2 * HIST);          // ~2.2 MB

  const size_t CNT_BYTES = (size_t)(530 + TT) * 512 * sizeof(int);
  hipMemsetAsync(cnt, 0, CNT_BYTES, stream);
  cvt_x_kernel<<<2048, 256, 0, stream>>>(x, Xbf);
  cvt_w_kernel<<<8192, 256, 0, stream>>>(W0, W0s);
  cvt_w_kernel<<<8192, 256, 0, stream>>>(W1, W1s);
  init_state_kernel<<<256, 256, 0, stream>>>(h0in, h0hist, h1hist);

  lstm_persist<<<256, 512, 0, stream>>>(W0s, W1s, b0, b1, Xbf,
                                        h0hist, h1hist, c0in, out, cnt);
}